// Round 1
// baseline (1882.302 us; speedup 1.0000x reference)
//
#include <hip/hip_runtime.h>
#include <math.h>

// Problem constants (from reference)
#define NN   2048   // nodes
#define DIN_ 128
#define DD   256
#define LL   4
#define HH   8
#define FF_  1024
#define EE   65536
#define DE_  16
#define HD_  32

__device__ __forceinline__ float gelu_f(float x){
  return 0.5f*x*(1.0f+erff(x*0.70710678118654752440f));
}

// block of 256 threads: sum across block, result broadcast to all threads
__device__ __forceinline__ float block_sum256(float v, float* sbuf){
  #pragma unroll
  for(int o=32;o>0;o>>=1) v += __shfl_xor(v,o);
  __syncthreads();
  if((threadIdx.x&63)==0) sbuf[threadIdx.x>>6]=v;
  __syncthreads();
  return sbuf[0]+sbuf[1]+sbuf[2]+sbuf[3];
}

// ---------------- edge projection + row L2 norm ----------------
// edge_w[e] = || edge_attr[e] @ ew_w + ew_b ||_2   ; 4 edges per block, 64 lanes/edge
__global__ __launch_bounds__(256) void edgew_kernel(const float* __restrict__ EA,
    const float* __restrict__ EW, const float* __restrict__ EB,
    float* __restrict__ edge_w){
  __shared__ float Ws[DE_][DD];
  int tid = threadIdx.x;
  for(int idx=tid; idx<DE_*DD/4; idx+=256)
    ((float4*)Ws)[idx] = ((const float4*)EW)[idx];
  __syncthreads();
  int e    = blockIdx.x*4 + (tid>>6);
  int lane = tid&63;
  float ea[DE_];
  #pragma unroll
  for(int k=0;k<DE_;k++) ea[k] = EA[(size_t)e*DE_ + k];
  float4 b4 = *(const float4*)&EB[lane*4];
  float y0=b4.x, y1=b4.y, y2=b4.z, y3=b4.w;
  #pragma unroll
  for(int k=0;k<DE_;k++){
    float a = ea[k];
    float4 w4 = *(float4*)&Ws[k][lane*4];
    y0 += a*w4.x; y1 += a*w4.y; y2 += a*w4.z; y3 += a*w4.w;
  }
  float ss = y0*y0+y1*y1+y2*y2+y3*y3;
  #pragma unroll
  for(int o=32;o>0;o>>=1) ss += __shfl_xor(ss,o);
  if(lane==0) edge_w[e] = sqrtf(ss);
}

// ---------------- CSR build ----------------
__global__ void count_kernel(const int* __restrict__ ei, int* __restrict__ counts){
  int e = blockIdx.x*256+threadIdx.x;
  if(e<EE) atomicAdd(&counts[ei[EE+e]], 1);
}

// one block of 1024 threads: exclusive scan of counts[2048] -> row_ptr, plus dinv
__global__ __launch_bounds__(1024) void scan_kernel(const int* __restrict__ counts,
    int* __restrict__ row_ptr, float* __restrict__ dinv){
  __shared__ int p[1024];
  int t = threadIdx.x;
  int c0 = counts[2*t], c1 = counts[2*t+1];
  p[t] = c0+c1;
  __syncthreads();
  for(int off=1; off<1024; off<<=1){
    int v = (t>=off) ? p[t-off] : 0;
    __syncthreads();
    p[t] += v;
    __syncthreads();
  }
  int incl = p[t];
  int excl = incl - (c0+c1);
  row_ptr[2*t]   = excl;
  row_ptr[2*t+1] = excl + c0;
  if(t==1023) row_ptr[2048] = incl;
  dinv[2*t]   = rsqrtf((float)c0 + 1.0f);
  dinv[2*t+1] = rsqrtf((float)c1 + 1.0f);
}

__global__ void bucket_kernel(const int* __restrict__ ei, const float* __restrict__ edge_w,
    const float* __restrict__ dinv, const int* __restrict__ row_ptr,
    int* __restrict__ cursor, int* __restrict__ csr_src, float* __restrict__ csr_c){
  int e = blockIdx.x*256+threadIdx.x;
  if(e>=EE) return;
  int s = ei[e], d = ei[EE+e];
  int pos = row_ptr[d] + atomicAdd(&cursor[d],1);
  csr_src[pos] = s;
  csr_c[pos]   = edge_w[e]*dinv[s];
}

// ---------------- GCN aggregation: one block per destination node ----------------
// out[n] = (sum_{e: dst=n} h[src]*c) * dinv[n] + h[n]
__global__ __launch_bounds__(256) void agg_kernel(const float* __restrict__ h,
    const int* __restrict__ row_ptr, const int* __restrict__ csr_src,
    const float* __restrict__ csr_c, const float* __restrict__ dinv,
    float* __restrict__ out){
  int n = blockIdx.x, d = threadIdx.x;
  float acc = 0.f;
  int beg = row_ptr[n], end = row_ptr[n+1];
  for(int i=beg;i<end;++i){
    acc += h[(size_t)csr_src[i]*DD + d]*csr_c[i];
  }
  out[(size_t)n*DD+d] = acc*dinv[n] + h[(size_t)n*DD+d];
}

// ---------------- generic tiled f32 GEMM: C = epi(A@W + bias [, res]) ----------------
// EPI: 0 = bias only, 1 = bias+gelu, 2 = bias+residual
template<int EPI>
__global__ __launch_bounds__(256) void gemm_kernel(const float* __restrict__ A,
    const float* __restrict__ W, const float* __restrict__ bias,
    const float* __restrict__ res, float* __restrict__ C,
    int M, int K, int Nc){
  __shared__ float As[16][64];
  __shared__ float Ws[16][64];
  const int m0 = blockIdx.y*64, n0 = blockIdx.x*64;
  const int tid = threadIdx.x;
  const int ty = tid>>4, tx = tid&15;
  float acc[4][4];
  #pragma unroll
  for(int i=0;i<4;i++)
    #pragma unroll
    for(int j=0;j<4;j++) acc[i][j]=0.f;
  const int am = tid>>2, ak = (tid&3)<<2;
  const int wk = tid>>4, wn = (tid&15)<<2;
  for(int k0=0;k0<K;k0+=16){
    __syncthreads();
    float4 a4 = *(const float4*)&A[(size_t)(m0+am)*K + k0+ak];
    As[ak+0][am]=a4.x; As[ak+1][am]=a4.y; As[ak+2][am]=a4.z; As[ak+3][am]=a4.w;
    *(float4*)&Ws[wk][wn] = *(const float4*)&W[(size_t)(k0+wk)*Nc + n0+wn];
    __syncthreads();
    #pragma unroll
    for(int k=0;k<16;k++){
      float4 av4 = *(float4*)&As[k][ty*4];
      float4 bv4 = *(float4*)&Ws[k][tx*4];
      float av[4]={av4.x,av4.y,av4.z,av4.w};
      float bv[4]={bv4.x,bv4.y,bv4.z,bv4.w};
      #pragma unroll
      for(int i=0;i<4;i++)
        #pragma unroll
        for(int j=0;j<4;j++) acc[i][j] += av[i]*bv[j];
    }
  }
  float4 b4 = *(const float4*)&bias[n0+tx*4];
  float bb[4]={b4.x,b4.y,b4.z,b4.w};
  #pragma unroll
  for(int i=0;i<4;i++){
    int m = m0+ty*4+i;
    size_t base = (size_t)m*Nc + n0+tx*4;
    float v[4];
    #pragma unroll
    for(int j=0;j<4;j++){
      v[j] = acc[i][j]+bb[j];
      if(EPI==1) v[j] = gelu_f(v[j]);
    }
    if(EPI==2){
      float4 r4 = *(const float4*)&res[base];
      v[0]+=r4.x; v[1]+=r4.y; v[2]+=r4.z; v[3]+=r4.w;
    }
    *(float4*)&C[base] = make_float4(v[0],v[1],v[2],v[3]);
  }
}

// ---------------- row LayerNorm ----------------
__global__ __launch_bounds__(256) void ln_kernel(const float* __restrict__ in,
    const float* __restrict__ g, const float* __restrict__ b, float* __restrict__ out){
  __shared__ float sbuf[4];
  int n = blockIdx.x, d = threadIdx.x;
  float v = in[(size_t)n*DD+d];
  float s  = block_sum256(v, sbuf);
  float s2 = block_sum256(v*v, sbuf);
  float m = s*(1.0f/DD);
  float var = s2*(1.0f/DD) - m*m;
  float r = rsqrtf(var + 1e-5f);
  out[(size_t)n*DD+d] = (v-m)*r*g[d] + b[d];
}

// ---------------- flash attention (f32), TQ=32 q-rows x TK=64 keys per tile ----------------
#define TQ 32
#define TK 64
__global__ __launch_bounds__(256) void attn_kernel(const float* __restrict__ Q,
    const float* __restrict__ K, const float* __restrict__ V,
    const float* __restrict__ bias, float* __restrict__ O){
  __shared__ float Ks[TK][36];   // pad 36: lanes (g varies) hit distinct banks
  __shared__ float Vs[TK][36];
  __shared__ float Bs[TQ][68];   // pad 68: rows shifted by 4 banks
  __shared__ float Ps[TQ][68];
  const int hh = blockIdx.y;
  const int q0 = blockIdx.x*TQ;
  const int tid = threadIdx.x;
  const int q = tid>>3;          // 0..31
  const int g = tid&7;           // 0..7
  float4 qv[8];
  #pragma unroll
  for(int j=0;j<8;j++) qv[j] = *(const float4*)&Q[(size_t)(q0+q)*DD + hh*HD_ + j*4];
  float m_run = -1e30f, lsum = 0.f;
  float acc[4] = {0.f,0.f,0.f,0.f};
  const float inv_scale = 0.17677669529663687f;  // 1/sqrt(32)
  for(int k0=0;k0<NN;k0+=TK){
    __syncthreads();
    for(int idx=tid; idx<TK*8; idx+=256){
      int kk = idx>>3, j4 = (idx&7)<<2;
      *(float4*)&Ks[kk][j4] = *(const float4*)&K[(size_t)(k0+kk)*DD + hh*HD_ + j4];
      *(float4*)&Vs[kk][j4] = *(const float4*)&V[(size_t)(k0+kk)*DD + hh*HD_ + j4];
    }
    for(int idx=tid; idx<TQ*TK; idx+=256){
      int qq = idx>>6, kk = idx&63;
      Bs[qq][kk] = bias[(size_t)(q0+qq)*(NN*HH) + (size_t)(k0+kk)*HH + hh];
    }
    __syncthreads();
    float s[8]; float mt = -1e30f;
    #pragma unroll
    for(int j=0;j<8;j++){
      int kk = g + 8*j;          // lanes in a g-group read distinct Ks rows
      float dot = 0.f;
      #pragma unroll
      for(int j4=0;j4<8;j4++){
        float4 kv = *(float4*)&Ks[kk][j4*4];
        dot += qv[j4].x*kv.x + qv[j4].y*kv.y + qv[j4].z*kv.z + qv[j4].w*kv.w;
      }
      s[j] = dot*inv_scale + Bs[q][kk];
      mt = fmaxf(mt, s[j]);
    }
    mt = fmaxf(mt, __shfl_xor(mt,1));
    mt = fmaxf(mt, __shfl_xor(mt,2));
    mt = fmaxf(mt, __shfl_xor(mt,4));
    float m_new = fmaxf(m_run, mt);
    float alpha = __expf(m_run - m_new);
    float ps = 0.f;
    #pragma unroll
    for(int j=0;j<8;j++){
      float p = __expf(s[j]-m_new);
      Ps[q][g+8*j] = p;
      ps += p;
    }
    lsum = lsum*alpha + ps;
    #pragma unroll
    for(int c=0;c<4;c++) acc[c]*=alpha;
    m_run = m_new;
    __syncthreads();
    #pragma unroll 8
    for(int kk=0;kk<TK;kk+=4){
      float4 p4 = *(float4*)&Ps[q][kk];
      float pv[4]={p4.x,p4.y,p4.z,p4.w};
      #pragma unroll
      for(int u=0;u<4;u++){
        float4 v4 = *(float4*)&Vs[kk+u][g*4];
        acc[0]+=pv[u]*v4.x; acc[1]+=pv[u]*v4.y; acc[2]+=pv[u]*v4.z; acc[3]+=pv[u]*v4.w;
      }
    }
  }
  lsum += __shfl_xor(lsum,1);
  lsum += __shfl_xor(lsum,2);
  lsum += __shfl_xor(lsum,4);
  float inv_l = 1.0f/lsum;
  *(float4*)&O[(size_t)(q0+q)*DD + hh*HD_ + g*4] =
      make_float4(acc[0]*inv_l, acc[1]*inv_l, acc[2]*inv_l, acc[3]*inv_l);
}

// ---------------- gated fusion ----------------
__global__ __launch_bounds__(256) void gate_kernel(const float* __restrict__ hl,
    const float* __restrict__ hgl, const float* __restrict__ gw,
    const float* __restrict__ gb, float* __restrict__ h){
  __shared__ float sbuf[4];
  int n = blockIdx.x, d = threadIdx.x;
  float a = hl[(size_t)n*DD+d], b2 = hgl[(size_t)n*DD+d];
  float p = a*gw[d] + b2*gw[DD+d];
  float s = block_sum256(p, sbuf);
  float gg = 1.0f/(1.0f+__expf(-(s+gb[0])));
  h[(size_t)n*DD+d] = gg*a + (1.0f-gg)*b2;
}

// ---------------- column mean of final output ----------------
__global__ __launch_bounds__(256) void mean_kernel(const float* __restrict__ o,
    float* __restrict__ mean){
  int d = threadIdx.x;
  int r0 = blockIdx.x*256;
  float acc = 0.f;
  for(int r=r0;r<r0+256;++r) acc += o[(size_t)r*DD+d];
  atomicAdd(&mean[d], acc*(1.0f/NN));
}

static inline void gemm_launch(int epi, const float* A, const float* W,
    const float* bias, const float* res, float* C, int M, int K, int Nc,
    hipStream_t s){
  dim3 g(Nc/64, M/64), b(256);
  if(epi==0)      hipLaunchKernelGGL((gemm_kernel<0>), g,b,0,s, A,W,bias,res,C,M,K,Nc);
  else if(epi==1) hipLaunchKernelGGL((gemm_kernel<1>), g,b,0,s, A,W,bias,res,C,M,K,Nc);
  else            hipLaunchKernelGGL((gemm_kernel<2>), g,b,0,s, A,W,bias,res,C,M,K,Nc);
}

extern "C" void kernel_launch(void* const* d_in, const int* in_sizes, int n_in,
                              void* d_out, int out_size, void* d_ws, size_t ws_size,
                              hipStream_t stream){
  const float* x         = (const float*)d_in[0];
  const int*   ei        = (const int*)  d_in[1];
  const float* edge_attr = (const float*)d_in[2];
  const float* attn_bias = (const float*)d_in[3];
  const float* in_w=(const float*)d_in[4];  const float* in_b=(const float*)d_in[5];
  const float* ew_w=(const float*)d_in[6];  const float* ew_b=(const float*)d_in[7];
  const float* lw =(const float*)d_in[8];   const float* lb =(const float*)d_in[9];
  const float* lng=(const float*)d_in[10];  const float* lnb=(const float*)d_in[11];
  const float* qw =(const float*)d_in[12];  const float* qb =(const float*)d_in[13];
  const float* kw =(const float*)d_in[14];  const float* kb =(const float*)d_in[15];
  const float* vw =(const float*)d_in[16];  const float* vb =(const float*)d_in[17];
  const float* ow =(const float*)d_in[18];  const float* ob =(const float*)d_in[19];
  const float* f1w=(const float*)d_in[20];  const float* f1b=(const float*)d_in[21];
  const float* f2w=(const float*)d_in[22];  const float* f2b=(const float*)d_in[23];
  const float* n1g=(const float*)d_in[24];  const float* n1b=(const float*)d_in[25];
  const float* n2g=(const float*)d_in[26];  const float* n2b=(const float*)d_in[27];
  const float* gw =(const float*)d_in[28];  const float* gb =(const float*)d_in[29];
  const float* fng=(const float*)d_in[30];  const float* fnb=(const float*)d_in[31];
  float* out = (float*)d_out;

  // workspace layout (floats); total ~32.3 MB
  float* ws    = (float*)d_ws;
  const size_t ND = (size_t)NN*DD;
  float* h     = ws;
  float* bufA  = h    + ND;
  float* bufB  = bufA + ND;
  float* hloc  = bufB + ND;
  float* hn    = hloc + ND;
  float* Qb    = hn   + ND;
  float* Kb    = Qb   + ND;
  float* Vb    = Kb   + ND;
  float* Ob    = Vb   + ND;
  float* hg    = Ob   + ND;
  float* hgl   = hg   + ND;
  float* ffb   = hgl  + ND;                 // NN*FF_
  float* edge_w= ffb  + (size_t)NN*FF_;
  float* csr_c = edge_w + EE;
  float* dinv  = csr_c  + EE;
  int* counts  = (int*)(dinv + NN);
  int* cursor  = counts + NN;
  int* row_ptr = cursor + NN;               // NN+1
  int* csr_src = row_ptr + NN + 64;         // padded start

  // ---- preprocessing (identical every call) ----
  hipMemsetAsync(counts, 0, NN*sizeof(int), stream);
  hipMemsetAsync(cursor, 0, NN*sizeof(int), stream);
  hipLaunchKernelGGL(count_kernel, dim3(EE/256),dim3(256),0,stream, ei, counts);
  hipLaunchKernelGGL(scan_kernel,  dim3(1),dim3(1024),0,stream, counts, row_ptr, dinv);
  hipLaunchKernelGGL(edgew_kernel, dim3(EE/4),dim3(256),0,stream, edge_attr, ew_w, ew_b, edge_w);
  hipLaunchKernelGGL(bucket_kernel,dim3(EE/256),dim3(256),0,stream, ei, edge_w, dinv, row_ptr, cursor, csr_src, csr_c);
  // h = x @ in_w + in_b
  gemm_launch(0, x, in_w, in_b, nullptr, h, NN, DIN_, DD, stream);

  for(int i=0;i<LL;i++){
    const float* lwi=lw+(size_t)i*DD*DD;   const float* lbi=lb+i*DD;
    const float* qwi=qw+(size_t)i*DD*DD;   const float* qbi=qb+i*DD;
    const float* kwi=kw+(size_t)i*DD*DD;   const float* kbi=kb+i*DD;
    const float* vwi=vw+(size_t)i*DD*DD;   const float* vbi=vb+i*DD;
    const float* owi=ow+(size_t)i*DD*DD;   const float* obi=ob+i*DD;
    const float* f1wi=f1w+(size_t)i*DD*FF_; const float* f1bi=f1b+i*FF_;
    const float* f2wi=f2w+(size_t)i*FF_*DD; const float* f2bi=f2b+i*DD;

    // local GCN branch
    hipLaunchKernelGGL(agg_kernel, dim3(NN),dim3(256),0,stream, h, row_ptr, csr_src, csr_c, dinv, bufA);
    gemm_launch(1, bufA, lwi, lbi, nullptr, bufB, NN, DD, DD, stream);     // gelu(agg@lw+lb)
    hipLaunchKernelGGL(ln_kernel, dim3(NN),dim3(256),0,stream, bufB, lng+i*DD, lnb+i*DD, hloc);

    // global attention branch
    hipLaunchKernelGGL(ln_kernel, dim3(NN),dim3(256),0,stream, h, n1g+i*DD, n1b+i*DD, hn);
    gemm_launch(0, hn, qwi, qbi, nullptr, Qb, NN, DD, DD, stream);
    gemm_launch(0, hn, kwi, kbi, nullptr, Kb, NN, DD, DD, stream);
    gemm_launch(0, hn, vwi, vbi, nullptr, Vb, NN, DD, DD, stream);
    hipLaunchKernelGGL(attn_kernel, dim3(NN/TQ, HH),dim3(256),0,stream, Qb, Kb, Vb, attn_bias, Ob);
    gemm_launch(2, Ob, owi, obi, h, hg, NN, DD, DD, stream);               // hg = h + o@ow+ob

    hipLaunchKernelGGL(ln_kernel, dim3(NN),dim3(256),0,stream, hg, n2g+i*DD, n2b+i*DD, hn);
    gemm_launch(1, hn, f1wi, f1bi, nullptr, ffb, NN, DD, FF_, stream);     // gelu(ln@f1w+f1b)
    gemm_launch(2, ffb, f2wi, f2bi, hg, hgl, NN, FF_, DD, stream);         // hglobal = hg + ff

    // gated fusion -> h
    hipLaunchKernelGGL(gate_kernel, dim3(NN),dim3(256),0,stream, hloc, hgl, gw+(size_t)i*2*DD, gb+i, h);
  }

  // final LN -> out[0:NN*DD], then column mean -> out[NN*DD : NN*DD+DD]
  hipLaunchKernelGGL(ln_kernel, dim3(NN),dim3(256),0,stream, h, fng, fnb, out);
  hipMemsetAsync(out + ND, 0, DD*sizeof(float), stream);
  hipLaunchKernelGGL(mean_kernel, dim3(NN/256),dim3(256),0,stream, out, out + ND);
}

// Round 2
// 1392.974 us; speedup vs baseline: 1.3513x; 1.3513x over previous
//
#include <hip/hip_runtime.h>
#include <math.h>

// Problem constants (from reference)
#define NN   2048   // nodes
#define DIN_ 128
#define DD   256
#define LL   4
#define HH   8
#define FF_  1024
#define EE   65536
#define DE_  16
#define HD_  32

typedef short bf16x8 __attribute__((ext_vector_type(8)));
typedef float f32x4  __attribute__((ext_vector_type(4)));

__device__ __forceinline__ float gelu_f(float x){
  return 0.5f*x*(1.0f+erff(x*0.70710678118654752440f));
}

__device__ __forceinline__ unsigned short f2bf(float x){
  unsigned int u = __builtin_bit_cast(unsigned int, x);
  unsigned int r = (u + 0x7fffu + ((u>>16)&1u)) >> 16;
  return (unsigned short)r;
}
__device__ __forceinline__ float bf2f(unsigned short b){
  unsigned int u = ((unsigned int)b)<<16;
  return __builtin_bit_cast(float, u);
}

// block of 256 threads: sum across block, result broadcast to all threads
__device__ __forceinline__ float block_sum256(float v, float* sbuf){
  #pragma unroll
  for(int o=32;o>0;o>>=1) v += __shfl_xor(v,o);
  __syncthreads();
  if((threadIdx.x&63)==0) sbuf[threadIdx.x>>6]=v;
  __syncthreads();
  return sbuf[0]+sbuf[1]+sbuf[2]+sbuf[3];
}

// ---------------- edge projection + row L2 norm ----------------
__global__ __launch_bounds__(256) void edgew_kernel(const float* __restrict__ EA,
    const float* __restrict__ EW, const float* __restrict__ EB,
    float* __restrict__ edge_w){
  __shared__ float Ws[DE_][DD];
  int tid = threadIdx.x;
  for(int idx=tid; idx<DE_*DD/4; idx+=256)
    ((float4*)Ws)[idx] = ((const float4*)EW)[idx];
  __syncthreads();
  int e    = blockIdx.x*4 + (tid>>6);
  int lane = tid&63;
  float ea[DE_];
  #pragma unroll
  for(int k=0;k<DE_;k++) ea[k] = EA[(size_t)e*DE_ + k];
  float4 b4 = *(const float4*)&EB[lane*4];
  float y0=b4.x, y1=b4.y, y2=b4.z, y3=b4.w;
  #pragma unroll
  for(int k=0;k<DE_;k++){
    float a = ea[k];
    float4 w4 = *(float4*)&Ws[k][lane*4];
    y0 += a*w4.x; y1 += a*w4.y; y2 += a*w4.z; y3 += a*w4.w;
  }
  float ss = y0*y0+y1*y1+y2*y2+y3*y3;
  #pragma unroll
  for(int o=32;o>0;o>>=1) ss += __shfl_xor(ss,o);
  if(lane==0) edge_w[e] = sqrtf(ss);
}

// ---------------- CSR build ----------------
__global__ void count_kernel(const int* __restrict__ ei, int* __restrict__ counts){
  int e = blockIdx.x*256+threadIdx.x;
  if(e<EE) atomicAdd(&counts[ei[EE+e]], 1);
}

__global__ __launch_bounds__(1024) void scan_kernel(const int* __restrict__ counts,
    int* __restrict__ row_ptr, float* __restrict__ dinv){
  __shared__ int p[1024];
  int t = threadIdx.x;
  int c0 = counts[2*t], c1 = counts[2*t+1];
  p[t] = c0+c1;
  __syncthreads();
  for(int off=1; off<1024; off<<=1){
    int v = (t>=off) ? p[t-off] : 0;
    __syncthreads();
    p[t] += v;
    __syncthreads();
  }
  int incl = p[t];
  int excl = incl - (c0+c1);
  row_ptr[2*t]   = excl;
  row_ptr[2*t+1] = excl + c0;
  if(t==1023) row_ptr[2048] = incl;
  dinv[2*t]   = rsqrtf((float)c0 + 1.0f);
  dinv[2*t+1] = rsqrtf((float)c1 + 1.0f);
}

__global__ void bucket_kernel(const int* __restrict__ ei, const float* __restrict__ edge_w,
    const float* __restrict__ dinv, const int* __restrict__ row_ptr,
    int* __restrict__ cursor, int* __restrict__ csr_src, float* __restrict__ csr_c){
  int e = blockIdx.x*256+threadIdx.x;
  if(e>=EE) return;
  int s = ei[e], d = ei[EE+e];
  int pos = row_ptr[d] + atomicAdd(&cursor[d],1);
  csr_src[pos] = s;
  csr_c[pos]   = edge_w[e]*dinv[s];
}

// ---------------- GCN aggregation ----------------
__global__ __launch_bounds__(256) void agg_kernel(const float* __restrict__ h,
    const int* __restrict__ row_ptr, const int* __restrict__ csr_src,
    const float* __restrict__ csr_c, const float* __restrict__ dinv,
    float* __restrict__ out){
  int n = blockIdx.x, d = threadIdx.x;
  float acc = 0.f;
  int beg = row_ptr[n], end = row_ptr[n+1];
  for(int i=beg;i<end;++i){
    acc += h[(size_t)csr_src[i]*DD + d]*csr_c[i];
  }
  out[(size_t)n*DD+d] = acc*dinv[n] + h[(size_t)n*DD+d];
}

// ---------------- generic tiled f32 GEMM ----------------
template<int EPI>
__global__ __launch_bounds__(256) void gemm_kernel(const float* __restrict__ A,
    const float* __restrict__ W, const float* __restrict__ bias,
    const float* __restrict__ res, float* __restrict__ C,
    int M, int K, int Nc){
  __shared__ float As[16][64];
  __shared__ float Ws[16][64];
  const int m0 = blockIdx.y*64, n0 = blockIdx.x*64;
  const int tid = threadIdx.x;
  const int ty = tid>>4, tx = tid&15;
  float acc[4][4];
  #pragma unroll
  for(int i=0;i<4;i++)
    #pragma unroll
    for(int j=0;j<4;j++) acc[i][j]=0.f;
  const int am = tid>>2, ak = (tid&3)<<2;
  const int wk = tid>>4, wn = (tid&15)<<2;
  for(int k0=0;k0<K;k0+=16){
    __syncthreads();
    float4 a4 = *(const float4*)&A[(size_t)(m0+am)*K + k0+ak];
    As[ak+0][am]=a4.x; As[ak+1][am]=a4.y; As[ak+2][am]=a4.z; As[ak+3][am]=a4.w;
    *(float4*)&Ws[wk][wn] = *(const float4*)&W[(size_t)(k0+wk)*Nc + n0+wn];
    __syncthreads();
    #pragma unroll
    for(int k=0;k<16;k++){
      float4 av4 = *(float4*)&As[k][ty*4];
      float4 bv4 = *(float4*)&Ws[k][tx*4];
      float av[4]={av4.x,av4.y,av4.z,av4.w};
      float bv[4]={bv4.x,bv4.y,bv4.z,bv4.w};
      #pragma unroll
      for(int i=0;i<4;i++)
        #pragma unroll
        for(int j=0;j<4;j++) acc[i][j] += av[i]*bv[j];
    }
  }
  float4 b4 = *(const float4*)&bias[n0+tx*4];
  float bb[4]={b4.x,b4.y,b4.z,b4.w};
  #pragma unroll
  for(int i=0;i<4;i++){
    int m = m0+ty*4+i;
    size_t base = (size_t)m*Nc + n0+tx*4;
    float v[4];
    #pragma unroll
    for(int j=0;j<4;j++){
      v[j] = acc[i][j]+bb[j];
      if(EPI==1) v[j] = gelu_f(v[j]);
    }
    if(EPI==2){
      float4 r4 = *(const float4*)&res[base];
      v[0]+=r4.x; v[1]+=r4.y; v[2]+=r4.z; v[3]+=r4.w;
    }
    *(float4*)&C[base] = make_float4(v[0],v[1],v[2],v[3]);
  }
}

// ---------------- row LayerNorm ----------------
__global__ __launch_bounds__(256) void ln_kernel(const float* __restrict__ in,
    const float* __restrict__ g, const float* __restrict__ b, float* __restrict__ out){
  __shared__ float sbuf[4];
  int n = blockIdx.x, d = threadIdx.x;
  float v = in[(size_t)n*DD+d];
  float s  = block_sum256(v, sbuf);
  float s2 = block_sum256(v*v, sbuf);
  float m = s*(1.0f/DD);
  float var = s2*(1.0f/DD) - m*m;
  float r = rsqrtf(var + 1e-5f);
  out[(size_t)n*DD+d] = (v-m)*r*g[d] + b[d];
}

// ---------------- bias transpose: [N][N][8] f32 -> [8][N][N] bf16 ----------------
__global__ __launch_bounds__(256) void bias_prep_kernel(const float* __restrict__ B,
    unsigned short* __restrict__ Bt){
  size_t p = (size_t)blockIdx.x*256 + threadIdx.x;   // p = q*2048 + k
  const float4* src = (const float4*)(B + p*8);
  float4 a = src[0], b = src[1];
  float v[8] = {a.x,a.y,a.z,a.w,b.x,b.y,b.z,b.w};
  size_t q = p >> 11, k = p & 2047;
  #pragma unroll
  for(int h=0;h<8;h++) Bt[((size_t)h*NN + q)*NN + k] = f2bf(v[h]);
}

// ---------------- per-layer QKV bf16 prep ----------------
// Qb[h][n][hd] = Q[n][h*32+hd]/sqrt(32);  Kb[h][n][hd] = K[...];  Vt[h][hd][n] = V[...]
__global__ __launch_bounds__(256) void qkv_prep_kernel(const float* __restrict__ Q,
    const float* __restrict__ K, const float* __restrict__ V,
    unsigned short* __restrict__ Qb, unsigned short* __restrict__ Kb,
    unsigned short* __restrict__ Vt){
  int n = blockIdx.x, d = threadIdx.x;
  int h = d>>5, hd = d&31;
  float q = Q[(size_t)n*DD+d] * 0.17677669529663687f;
  float k = K[(size_t)n*DD+d];
  float v = V[(size_t)n*DD+d];
  Qb[((size_t)h*NN+n)*HD_+hd] = f2bf(q);
  Kb[((size_t)h*NN+n)*HD_+hd] = f2bf(k);
  Vt[((size_t)h*HD_+hd)*NN+n] = f2bf(v);
}

// ---------------- MFMA flash attention ----------------
// block = (q-tile of 64 rows, head). 4 waves, 16 q-rows each.
// QK^T: mfma_f32_16x16x32_bf16, contraction = HD=32; C-init = bias tile.
// PV:   mfma_f32_16x16x32_bf16, contraction over 64 keys in 2 chunks.
#define TQA 64
__global__ __launch_bounds__(256) void attn_mfma_kernel(
    const unsigned short* __restrict__ Qb,   // [8][2048][32] bf16 (pre-scaled)
    const unsigned short* __restrict__ Kb,   // [8][2048][32] bf16
    const unsigned short* __restrict__ Vt,   // [8][32][2048] bf16
    const unsigned short* __restrict__ Bt,   // [8][2048][2048] bf16
    float* __restrict__ O)                   // [2048][256] f32
{
  __shared__ short Ks[64*40];      // row stride 40 shorts (80 B): 2-way banks on b128 reads
  __shared__ short Vs[32*72];      // row stride 72 shorts (144 B)
  __shared__ short Ps[4][16*72];   // per-wave P tile [16 q][64 keys], padded
  const int h   = blockIdx.y;
  const int q0  = blockIdx.x * TQA;
  const int tid = threadIdx.x;
  const int w   = tid >> 6;
  const int l   = tid & 63;
  const int l15 = l & 15, lg = l >> 4;

  // Q A-fragment: row = q0 + w*16 + (l&15), k = (l>>4)*8 + j
  bf16x8 qf = *(const bf16x8*)&Qb[((size_t)h*NN + q0 + w*16 + l15)*HD_ + lg*8];

  const int kkey = tid >> 2, kg = tid & 3;   // K staging: key row, 16B chunk
  const int vhd  = tid >> 3, vg = tid & 7;   // V staging: hd row, 16B chunk

  const unsigned short* Kbase = Kb + (size_t)h*NN*HD_;
  const unsigned short* Vbase = Vt + (size_t)h*HD_*NN;
  const unsigned short* Bbase = Bt + (size_t)h*NN*NN + (size_t)(q0 + w*16 + lg*4)*NN + l15;

  f32x4 Oa0 = {0.f,0.f,0.f,0.f}, Oa1 = {0.f,0.f,0.f,0.f};
  float m_run[4] = {-1e30f,-1e30f,-1e30f,-1e30f};
  float l_run[4] = {0.f,0.f,0.f,0.f};
  short* Pw = &Ps[w][0];

  for(int kt=0; kt<NN; kt+=64){
    // issue global loads (independent of LDS)
    bf16x8 krow = *(const bf16x8*)&Kbase[(size_t)(kt + kkey)*HD_ + kg*8];
    bf16x8 vrow = *(const bf16x8*)&Vbase[(size_t)vhd*NN + kt + vg*8];
    f32x4 acc[4];
    #pragma unroll
    for(int t=0;t<4;t++){
      #pragma unroll
      for(int r=0;r<4;r++)
        acc[t][r] = bf2f(Bbase[(size_t)r*NN + kt + 16*t]);
    }
    __syncthreads();            // everyone done reading previous K/V tiles
    *(bf16x8*)&Ks[kkey*40 + kg*8] = krow;
    *(bf16x8*)&Vs[vhd*72 + vg*8]  = vrow;
    __syncthreads();

    // QK^T: S[16 q][64 keys], acc pre-loaded with bias
    #pragma unroll
    for(int t=0;t<4;t++){
      bf16x8 kf = *(const bf16x8*)&Ks[(16*t + l15)*40 + lg*8];
      acc[t] = __builtin_amdgcn_mfma_f32_16x16x32_bf16(qf, kf, acc[t], 0,0,0);
    }

    // online softmax (rows of lane = (l>>4)*4 + r; 16-lane group spans the 64 key-cols)
    #pragma unroll
    for(int r=0;r<4;r++){
      float m = fmaxf(fmaxf(acc[0][r],acc[1][r]), fmaxf(acc[2][r],acc[3][r]));
      m = fmaxf(m, __shfl_xor(m,1));
      m = fmaxf(m, __shfl_xor(m,2));
      m = fmaxf(m, __shfl_xor(m,4));
      m = fmaxf(m, __shfl_xor(m,8));
      float m_new = fmaxf(m_run[r], m);
      float alpha = __expf(m_run[r]-m_new);
      m_run[r] = m_new;
      float s = 0.f;
      #pragma unroll
      for(int t=0;t<4;t++){
        float p = __expf(acc[t][r]-m_new);
        acc[t][r] = p;
        s += p;
      }
      s += __shfl_xor(s,1);
      s += __shfl_xor(s,2);
      s += __shfl_xor(s,4);
      s += __shfl_xor(s,8);
      l_run[r] = l_run[r]*alpha + s;
      Oa0[r] *= alpha;
      Oa1[r] *= alpha;
      // write P row (bf16) to per-wave LDS tile: P[q=(l>>4)*4+r][key=16t+(l&15)]
      int q = lg*4 + r;
      #pragma unroll
      for(int t=0;t<4;t++)
        Pw[q*72 + 16*t + l15] = (short)f2bf(acc[t][r]);
    }

    // PV: O[16 q][32 hd] += P[16 q][64 k] * V[64 k][32 hd]
    #pragma unroll
    for(int chunk=0;chunk<2;chunk++){
      bf16x8 pf = *(const bf16x8*)&Pw[l15*72 + chunk*32 + lg*8];
      bf16x8 vf0 = *(const bf16x8*)&Vs[(     l15)*72 + chunk*32 + lg*8];
      bf16x8 vf1 = *(const bf16x8*)&Vs[(16 + l15)*72 + chunk*32 + lg*8];
      Oa0 = __builtin_amdgcn_mfma_f32_16x16x32_bf16(pf, vf0, Oa0, 0,0,0);
      Oa1 = __builtin_amdgcn_mfma_f32_16x16x32_bf16(pf, vf1, Oa1, 0,0,0);
    }
  }

  #pragma unroll
  for(int r=0;r<4;r++){
    float inv = 1.0f/l_run[r];
    size_t row = q0 + w*16 + lg*4 + r;
    O[row*DD + h*HD_ +      l15] = Oa0[r]*inv;
    O[row*DD + h*HD_ + 16 + l15] = Oa1[r]*inv;
  }
}

// ---------------- gated fusion ----------------
__global__ __launch_bounds__(256) void gate_kernel(const float* __restrict__ hl,
    const float* __restrict__ hgl, const float* __restrict__ gw,
    const float* __restrict__ gb, float* __restrict__ h){
  __shared__ float sbuf[4];
  int n = blockIdx.x, d = threadIdx.x;
  float a = hl[(size_t)n*DD+d], b2 = hgl[(size_t)n*DD+d];
  float p = a*gw[d] + b2*gw[DD+d];
  float s = block_sum256(p, sbuf);
  float gg = 1.0f/(1.0f+__expf(-(s+gb[0])));
  h[(size_t)n*DD+d] = gg*a + (1.0f-gg)*b2;
}

// ---------------- column mean ----------------
__global__ __launch_bounds__(256) void mean_kernel(const float* __restrict__ o,
    float* __restrict__ mean){
  int d = threadIdx.x;
  int r0 = blockIdx.x*256;
  float acc = 0.f;
  for(int r=r0;r<r0+256;++r) acc += o[(size_t)r*DD+d];
  atomicAdd(&mean[d], acc*(1.0f/NN));
}

static inline void gemm_launch(int epi, const float* A, const float* W,
    const float* bias, const float* res, float* C, int M, int K, int Nc,
    hipStream_t s){
  dim3 g(Nc/64, M/64), b(256);
  if(epi==0)      hipLaunchKernelGGL((gemm_kernel<0>), g,b,0,s, A,W,bias,res,C,M,K,Nc);
  else if(epi==1) hipLaunchKernelGGL((gemm_kernel<1>), g,b,0,s, A,W,bias,res,C,M,K,Nc);
  else            hipLaunchKernelGGL((gemm_kernel<2>), g,b,0,s, A,W,bias,res,C,M,K,Nc);
}

extern "C" void kernel_launch(void* const* d_in, const int* in_sizes, int n_in,
                              void* d_out, int out_size, void* d_ws, size_t ws_size,
                              hipStream_t stream){
  const float* x         = (const float*)d_in[0];
  const int*   ei        = (const int*)  d_in[1];
  const float* edge_attr = (const float*)d_in[2];
  const float* attn_bias = (const float*)d_in[3];
  const float* in_w=(const float*)d_in[4];  const float* in_b=(const float*)d_in[5];
  const float* ew_w=(const float*)d_in[6];  const float* ew_b=(const float*)d_in[7];
  const float* lw =(const float*)d_in[8];   const float* lb =(const float*)d_in[9];
  const float* lng=(const float*)d_in[10];  const float* lnb=(const float*)d_in[11];
  const float* qw =(const float*)d_in[12];  const float* qb =(const float*)d_in[13];
  const float* kw =(const float*)d_in[14];  const float* kb =(const float*)d_in[15];
  const float* vw =(const float*)d_in[16];  const float* vb =(const float*)d_in[17];
  const float* ow =(const float*)d_in[18];  const float* ob =(const float*)d_in[19];
  const float* f1w=(const float*)d_in[20];  const float* f1b=(const float*)d_in[21];
  const float* f2w=(const float*)d_in[22];  const float* f2b=(const float*)d_in[23];
  const float* n1g=(const float*)d_in[24];  const float* n1b=(const float*)d_in[25];
  const float* n2g=(const float*)d_in[26];  const float* n2b=(const float*)d_in[27];
  const float* gw =(const float*)d_in[28];  const float* gb =(const float*)d_in[29];
  const float* fng=(const float*)d_in[30];  const float* fnb=(const float*)d_in[31];
  float* out = (float*)d_out;

  // ---- workspace layout (byte-offset based, 256B aligned blocks) ----
  char* Wp = (char*)d_ws;
  auto alloc = [&](size_t bytes){ char* p = Wp; Wp += (bytes + 255) & ~(size_t)255; return p; };
  const size_t ND = (size_t)NN*DD;
  unsigned short* Bt   = (unsigned short*)alloc((size_t)HH*NN*NN*2);  // 64 MiB
  unsigned short* Qb16 = (unsigned short*)alloc(ND*2);
  unsigned short* Kb16 = (unsigned short*)alloc(ND*2);
  unsigned short* Vt16 = (unsigned short*)alloc(ND*2);
  float* h     = (float*)alloc(ND*4);
  float* bufA  = (float*)alloc(ND*4);
  float* bufB  = (float*)alloc(ND*4);
  float* hloc  = (float*)alloc(ND*4);
  float* hn    = (float*)alloc(ND*4);
  float* Qf    = (float*)alloc(ND*4);
  float* Kf    = (float*)alloc(ND*4);
  float* Vf    = (float*)alloc(ND*4);
  float* Ob    = (float*)alloc(ND*4);
  float* hg    = (float*)alloc(ND*4);
  float* hgl   = (float*)alloc(ND*4);
  float* ffb   = (float*)alloc((size_t)NN*FF_*4);
  float* edge_w= (float*)alloc(EE*4);
  float* csr_c = (float*)alloc(EE*4);
  float* dinv  = (float*)alloc(NN*4);
  int* counts  = (int*)alloc(NN*4);
  int* cursor  = (int*)alloc(NN*4);
  int* row_ptr = (int*)alloc((NN+1)*4);
  int* csr_src = (int*)alloc(EE*4);

  // ---- preprocessing (identical every call) ----
  hipMemsetAsync(counts, 0, NN*sizeof(int), stream);
  hipMemsetAsync(cursor, 0, NN*sizeof(int), stream);
  hipLaunchKernelGGL(count_kernel, dim3(EE/256),dim3(256),0,stream, ei, counts);
  hipLaunchKernelGGL(scan_kernel,  dim3(1),dim3(1024),0,stream, counts, row_ptr, dinv);
  hipLaunchKernelGGL(edgew_kernel, dim3(EE/4),dim3(256),0,stream, edge_attr, ew_w, ew_b, edge_w);
  hipLaunchKernelGGL(bucket_kernel,dim3(EE/256),dim3(256),0,stream, ei, edge_w, dinv, row_ptr, cursor, csr_src, csr_c);
  hipLaunchKernelGGL(bias_prep_kernel, dim3(NN*NN/256),dim3(256),0,stream, attn_bias, Bt);
  // h = x @ in_w + in_b
  gemm_launch(0, x, in_w, in_b, nullptr, h, NN, DIN_, DD, stream);

  for(int i=0;i<LL;i++){
    const float* lwi=lw+(size_t)i*DD*DD;   const float* lbi=lb+i*DD;
    const float* qwi=qw+(size_t)i*DD*DD;   const float* qbi=qb+i*DD;
    const float* kwi=kw+(size_t)i*DD*DD;   const float* kbi=kb+i*DD;
    const float* vwi=vw+(size_t)i*DD*DD;   const float* vbi=vb+i*DD;
    const float* owi=ow+(size_t)i*DD*DD;   const float* obi=ob+i*DD;
    const float* f1wi=f1w+(size_t)i*DD*FF_; const float* f1bi=f1b+i*FF_;
    const float* f2wi=f2w+(size_t)i*FF_*DD; const float* f2bi=f2b+i*DD;

    // local GCN branch
    hipLaunchKernelGGL(agg_kernel, dim3(NN),dim3(256),0,stream, h, row_ptr, csr_src, csr_c, dinv, bufA);
    gemm_launch(1, bufA, lwi, lbi, nullptr, bufB, NN, DD, DD, stream);
    hipLaunchKernelGGL(ln_kernel, dim3(NN),dim3(256),0,stream, bufB, lng+i*DD, lnb+i*DD, hloc);

    // global attention branch
    hipLaunchKernelGGL(ln_kernel, dim3(NN),dim3(256),0,stream, h, n1g+i*DD, n1b+i*DD, hn);
    gemm_launch(0, hn, qwi, qbi, nullptr, Qf, NN, DD, DD, stream);
    gemm_launch(0, hn, kwi, kbi, nullptr, Kf, NN, DD, DD, stream);
    gemm_launch(0, hn, vwi, vbi, nullptr, Vf, NN, DD, DD, stream);
    hipLaunchKernelGGL(qkv_prep_kernel, dim3(NN),dim3(256),0,stream, Qf, Kf, Vf, Qb16, Kb16, Vt16);
    hipLaunchKernelGGL(attn_mfma_kernel, dim3(NN/TQA, HH),dim3(256),0,stream,
                       Qb16, Kb16, Vt16, Bt, Ob);
    gemm_launch(2, Ob, owi, obi, h, hg, NN, DD, DD, stream);

    hipLaunchKernelGGL(ln_kernel, dim3(NN),dim3(256),0,stream, hg, n2g+i*DD, n2b+i*DD, hn);
    gemm_launch(1, hn, f1wi, f1bi, nullptr, ffb, NN, DD, FF_, stream);
    gemm_launch(2, ffb, f2wi, f2bi, hg, hgl, NN, FF_, DD, stream);

    // gated fusion -> h
    hipLaunchKernelGGL(gate_kernel, dim3(NN),dim3(256),0,stream, hloc, hgl, gw+(size_t)i*2*DD, gb+i, h);
  }

  // final LN -> out[0:NN*DD], then column mean -> out[NN*DD : +DD]
  hipLaunchKernelGGL(ln_kernel, dim3(NN),dim3(256),0,stream, h, fng, fnb, out);
  hipMemsetAsync(out + ND, 0, DD*sizeof(float), stream);
  hipLaunchKernelGGL(mean_kernel, dim3(NN/256),dim3(256),0,stream, out, out + ND);
}

// Round 3
// 809.892 us; speedup vs baseline: 2.3241x; 1.7200x over previous
//
#include <hip/hip_runtime.h>
#include <math.h>

// Problem constants (from reference)
#define NN   2048   // nodes
#define DIN_ 128
#define DD   256
#define LL   4
#define HH   8
#define FF_  1024
#define EE   65536
#define DE_  16
#define HD_  32

typedef short bf16x8 __attribute__((ext_vector_type(8)));
typedef float f32x4  __attribute__((ext_vector_type(4)));

__device__ __forceinline__ float gelu_f(float x){
  return 0.5f*x*(1.0f+erff(x*0.70710678118654752440f));
}

__device__ __forceinline__ unsigned short f2bf(float x){
  unsigned int u = __builtin_bit_cast(unsigned int, x);
  unsigned int r = (u + 0x7fffu + ((u>>16)&1u)) >> 16;
  return (unsigned short)r;
}
__device__ __forceinline__ float bf2f(unsigned short b){
  unsigned int u = ((unsigned int)b)<<16;
  return __builtin_bit_cast(float, u);
}

__device__ __forceinline__ float block_sum256(float v, float* sbuf){
  #pragma unroll
  for(int o=32;o>0;o>>=1) v += __shfl_xor(v,o);
  __syncthreads();
  if((threadIdx.x&63)==0) sbuf[threadIdx.x>>6]=v;
  __syncthreads();
  return sbuf[0]+sbuf[1]+sbuf[2]+sbuf[3];
}

// ---------------- edge projection + row L2 norm ----------------
__global__ __launch_bounds__(256) void edgew_kernel(const float* __restrict__ EA,
    const float* __restrict__ EW, const float* __restrict__ EB,
    float* __restrict__ edge_w){
  __shared__ float Ws[DE_][DD];
  int tid = threadIdx.x;
  for(int idx=tid; idx<DE_*DD/4; idx+=256)
    ((float4*)Ws)[idx] = ((const float4*)EW)[idx];
  __syncthreads();
  int e    = blockIdx.x*4 + (tid>>6);
  int lane = tid&63;
  float ea[DE_];
  #pragma unroll
  for(int k=0;k<DE_;k++) ea[k] = EA[(size_t)e*DE_ + k];
  float4 b4 = *(const float4*)&EB[lane*4];
  float y0=b4.x, y1=b4.y, y2=b4.z, y3=b4.w;
  #pragma unroll
  for(int k=0;k<DE_;k++){
    float a = ea[k];
    float4 w4 = *(float4*)&Ws[k][lane*4];
    y0 += a*w4.x; y1 += a*w4.y; y2 += a*w4.z; y3 += a*w4.w;
  }
  float ss = y0*y0+y1*y1+y2*y2+y3*y3;
  #pragma unroll
  for(int o=32;o>0;o>>=1) ss += __shfl_xor(ss,o);
  if(lane==0) edge_w[e] = sqrtf(ss);
}

// ---------------- CSR build ----------------
__global__ void count_kernel(const int* __restrict__ ei, int* __restrict__ counts){
  int e = blockIdx.x*256+threadIdx.x;
  if(e<EE) atomicAdd(&counts[ei[EE+e]], 1);
}

__global__ __launch_bounds__(1024) void scan_kernel(const int* __restrict__ counts,
    int* __restrict__ row_ptr, float* __restrict__ dinv){
  __shared__ int p[1024];
  int t = threadIdx.x;
  int c0 = counts[2*t], c1 = counts[2*t+1];
  p[t] = c0+c1;
  __syncthreads();
  for(int off=1; off<1024; off<<=1){
    int v = (t>=off) ? p[t-off] : 0;
    __syncthreads();
    p[t] += v;
    __syncthreads();
  }
  int incl = p[t];
  int excl = incl - (c0+c1);
  row_ptr[2*t]   = excl;
  row_ptr[2*t+1] = excl + c0;
  if(t==1023) row_ptr[2048] = incl;
  dinv[2*t]   = rsqrtf((float)c0 + 1.0f);
  dinv[2*t+1] = rsqrtf((float)c1 + 1.0f);
}

__global__ void bucket_kernel(const int* __restrict__ ei, const float* __restrict__ edge_w,
    const float* __restrict__ dinv, const int* __restrict__ row_ptr,
    int* __restrict__ cursor, int* __restrict__ csr_src, float* __restrict__ csr_c){
  int e = blockIdx.x*256+threadIdx.x;
  if(e>=EE) return;
  int s = ei[e], d = ei[EE+e];
  int pos = row_ptr[d] + atomicAdd(&cursor[d],1);
  csr_src[pos] = s;
  csr_c[pos]   = edge_w[e]*dinv[s];
}

// ---------------- GCN aggregation (bf16 out: feeds GEMM) ----------------
__global__ __launch_bounds__(256) void agg_kernel(const float* __restrict__ h,
    const int* __restrict__ row_ptr, const int* __restrict__ csr_src,
    const float* __restrict__ csr_c, const float* __restrict__ dinv,
    unsigned short* __restrict__ out){
  int n = blockIdx.x, d = threadIdx.x;
  float acc = 0.f;
  int beg = row_ptr[n], end = row_ptr[n+1];
  for(int i=beg;i<end;++i){
    acc += h[(size_t)csr_src[i]*DD + d]*csr_c[i];
  }
  out[(size_t)n*DD+d] = f2bf(acc*dinv[n] + h[(size_t)n*DD+d]);
}

// ---------------- weight transpose+cast: src f32 [K][N] -> dst bf16 [N][K] ----------------
__global__ __launch_bounds__(256) void wtrans_kernel(const float* __restrict__ src,
    unsigned short* __restrict__ dst, int K, int N,
    size_t srcMat, size_t dstMat, int dstRowOff){
  __shared__ float Ls[32][33];
  int z = blockIdx.z;
  const float* S = src + (size_t)z*srcMat;
  unsigned short* Dp = dst + (size_t)z*dstMat;
  int k0 = blockIdx.x*32, n0 = blockIdx.y*32;
  int tx = threadIdx.x&31, ty = threadIdx.x>>5;   // ty in 0..7
  #pragma unroll
  for(int i=0;i<4;i++)
    Ls[ty*4+i][tx] = S[(size_t)(k0+ty*4+i)*N + n0+tx];
  __syncthreads();
  #pragma unroll
  for(int i=0;i<4;i++)
    Dp[(size_t)(n0+ty*4+i+dstRowOff)*K + k0+tx] = f2bf(Ls[tx][ty*4+i]);
}

// concat qkv biases per layer into [L][768]
__global__ void qkvb_kernel(const float* __restrict__ qb, const float* __restrict__ kb,
    const float* __restrict__ vb, float* __restrict__ o){
  int idx = blockIdx.x*256+threadIdx.x;     // L*768
  int l = idx/768, c = idx%768;
  float v = (c<256) ? qb[l*DD+c] : (c<512 ? kb[l*DD+c-256] : vb[l*DD+c-512]);
  o[idx]=v;
}

__global__ void cast_bf_kernel(const float* __restrict__ in,
    unsigned short* __restrict__ out, int n){
  int i = blockIdx.x*256+threadIdx.x;
  if(i<n) out[i]=f2bf(in[i]);
}

// ---------------- MFMA GEMM: C = epi(A_bf16 @ BT_bf16^T + bias [,res]) ----------------
// A [M][K] bf16 row-major; BT [N][K] bf16 (pre-transposed weights).
// EPI: 0 bias, 1 bias+gelu, 2 bias+res.  OUT: 0 f32, 1 bf16, 2 qkv-layout scatter.
template<int EPI, int OUT>
__global__ __launch_bounds__(256) void mgemm_kernel(
    const unsigned short* __restrict__ A, const unsigned short* __restrict__ BT,
    const float* __restrict__ bias, const float* __restrict__ res,
    void* __restrict__ Cout, int M, int K, int N){
  __shared__ short As[64][72];
  __shared__ short Bs[64][72];
  const int m0 = blockIdx.y*64, n0 = blockIdx.x*64;
  const int tid = threadIdx.x;
  const int w = tid>>6, l = tid&63, l15 = l&15, lg = l>>4;
  const int wm = w>>1, wn = w&1;
  const int sr = tid>>2, sc = tid&3;
  f32x4 acc[2][2];
  #pragma unroll
  for(int a=0;a<2;a++)
    #pragma unroll
    for(int b2=0;b2<2;b2++) acc[a][b2]=(f32x4){0.f,0.f,0.f,0.f};

  for(int k0=0;k0<K;k0+=64){
    bf16x8 a0 = *(const bf16x8*)&A[(size_t)(m0+sr)*K + k0 + sc*8];
    bf16x8 a1 = *(const bf16x8*)&A[(size_t)(m0+sr)*K + k0 + (sc+4)*8];
    bf16x8 b0 = *(const bf16x8*)&BT[(size_t)(n0+sr)*K + k0 + sc*8];
    bf16x8 b1 = *(const bf16x8*)&BT[(size_t)(n0+sr)*K + k0 + (sc+4)*8];
    __syncthreads();
    *(bf16x8*)&As[sr][sc*8]     = a0;
    *(bf16x8*)&As[sr][(sc+4)*8] = a1;
    *(bf16x8*)&Bs[sr][sc*8]     = b0;
    *(bf16x8*)&Bs[sr][(sc+4)*8] = b1;
    __syncthreads();
    #pragma unroll
    for(int kk=0;kk<2;kk++){
      bf16x8 af[2], bfr[2];
      #pragma unroll
      for(int mi=0;mi<2;mi++) af[mi]  = *(const bf16x8*)&As[wm*32+mi*16+l15][kk*32+lg*8];
      #pragma unroll
      for(int ni=0;ni<2;ni++) bfr[ni] = *(const bf16x8*)&Bs[wn*32+ni*16+l15][kk*32+lg*8];
      #pragma unroll
      for(int mi=0;mi<2;mi++)
        #pragma unroll
        for(int ni=0;ni<2;ni++)
          acc[mi][ni] = __builtin_amdgcn_mfma_f32_16x16x32_bf16(af[mi], bfr[ni], acc[mi][ni], 0,0,0);
    }
  }

  const size_t NDq = (size_t)NN*DD;
  #pragma unroll
  for(int mi=0;mi<2;mi++){
    #pragma unroll
    for(int ni=0;ni<2;ni++){
      int cn = n0 + wn*32 + ni*16 + l15;
      float bb = bias[cn];
      #pragma unroll
      for(int r=0;r<4;r++){
        int cm = m0 + wm*32 + mi*16 + lg*4 + r;
        float v = acc[mi][ni][r] + bb;
        if(EPI==1) v = gelu_f(v);
        if(EPI==2) v += res[(size_t)cm*N + cn];
        if(OUT==0)      ((float*)Cout)[(size_t)cm*N + cn] = v;
        else if(OUT==1) ((unsigned short*)Cout)[(size_t)cm*N + cn] = f2bf(v);
        else{
          unsigned short* Cq = (unsigned short*)Cout;
          if(cn < 256){
            Cq[((size_t)(cn>>5)*NN + cm)*HD_ + (cn&31)] = f2bf(v*0.17677669529663687f);
          }else if(cn < 512){
            int c2 = cn-256;
            Cq[NDq + ((size_t)(c2>>5)*NN + cm)*HD_ + (c2&31)] = f2bf(v);
          }else{
            int c2 = cn-512;
            Cq[2*NDq + (size_t)c2*NN + cm] = f2bf(v);
          }
        }
      }
    }
  }
}

// ---------------- row LayerNorm (templated output dtype) ----------------
template<int OUTBF>
__global__ __launch_bounds__(256) void ln_kernel(const float* __restrict__ in,
    const float* __restrict__ g, const float* __restrict__ b, void* __restrict__ outp){
  __shared__ float sbuf[4];
  int n = blockIdx.x, d = threadIdx.x;
  float v = in[(size_t)n*DD+d];
  float s  = block_sum256(v, sbuf);
  float s2 = block_sum256(v*v, sbuf);
  float m = s*(1.0f/DD);
  float var = s2*(1.0f/DD) - m*m;
  float r = rsqrtf(var + 1e-5f);
  float y = (v-m)*r*g[d] + b[d];
  if(OUTBF) ((unsigned short*)outp)[(size_t)n*DD+d] = f2bf(y);
  else      ((float*)outp)[(size_t)n*DD+d] = y;
}

// ---------------- bias transpose: [N][N][8] f32 -> [8][N][N] bf16 ----------------
__global__ __launch_bounds__(256) void bias_prep_kernel(const float* __restrict__ B,
    unsigned short* __restrict__ Bt){
  size_t p = (size_t)blockIdx.x*256 + threadIdx.x;   // p = q*2048 + k
  const float4* src = (const float4*)(B + p*8);
  float4 a = src[0], b = src[1];
  float v[8] = {a.x,a.y,a.z,a.w,b.x,b.y,b.z,b.w};
  size_t q = p >> 11, k = p & 2047;
  #pragma unroll
  for(int h=0;h<8;h++) Bt[((size_t)h*NN + q)*NN + k] = f2bf(v[h]);
}

// ---------------- MFMA flash attention (bf16 out) ----------------
#define TQA 64
__global__ __launch_bounds__(256) void attn_mfma_kernel(
    const unsigned short* __restrict__ Qb,   // [8][2048][32] bf16 (pre-scaled)
    const unsigned short* __restrict__ Kb,   // [8][2048][32] bf16
    const unsigned short* __restrict__ Vt,   // [8][32][2048] bf16
    const unsigned short* __restrict__ Bt,   // [8][2048][2048] bf16
    unsigned short* __restrict__ O)          // [2048][256] bf16
{
  __shared__ short Ks[64*40];
  __shared__ short Vs[32*72];
  __shared__ short Ps[4][16*72];
  const int h   = blockIdx.y;
  const int q0  = blockIdx.x * TQA;
  const int tid = threadIdx.x;
  const int w   = tid >> 6;
  const int l   = tid & 63;
  const int l15 = l & 15, lg = l >> 4;

  bf16x8 qf = *(const bf16x8*)&Qb[((size_t)h*NN + q0 + w*16 + l15)*HD_ + lg*8];

  const int kkey = tid >> 2, kg = tid & 3;
  const int vhd  = tid >> 3, vg = tid & 7;

  const unsigned short* Kbase = Kb + (size_t)h*NN*HD_;
  const unsigned short* Vbase = Vt + (size_t)h*HD_*NN;
  const unsigned short* Bbase = Bt + (size_t)h*NN*NN + (size_t)(q0 + w*16 + lg*4)*NN + l15;

  f32x4 Oa0 = {0.f,0.f,0.f,0.f}, Oa1 = {0.f,0.f,0.f,0.f};
  float m_run[4] = {-1e30f,-1e30f,-1e30f,-1e30f};
  float l_run[4] = {0.f,0.f,0.f,0.f};
  short* Pw = &Ps[w][0];

  for(int kt=0; kt<NN; kt+=64){
    bf16x8 krow = *(const bf16x8*)&Kbase[(size_t)(kt + kkey)*HD_ + kg*8];
    bf16x8 vrow = *(const bf16x8*)&Vbase[(size_t)vhd*NN + kt + vg*8];
    f32x4 acc[4];
    #pragma unroll
    for(int t=0;t<4;t++){
      #pragma unroll
      for(int r=0;r<4;r++)
        acc[t][r] = bf2f(Bbase[(size_t)r*NN + kt + 16*t]);
    }
    __syncthreads();
    *(bf16x8*)&Ks[kkey*40 + kg*8] = krow;
    *(bf16x8*)&Vs[vhd*72 + vg*8]  = vrow;
    __syncthreads();

    #pragma unroll
    for(int t=0;t<4;t++){
      bf16x8 kf = *(const bf16x8*)&Ks[(16*t + l15)*40 + lg*8];
      acc[t] = __builtin_amdgcn_mfma_f32_16x16x32_bf16(qf, kf, acc[t], 0,0,0);
    }

    #pragma unroll
    for(int r=0;r<4;r++){
      float m = fmaxf(fmaxf(acc[0][r],acc[1][r]), fmaxf(acc[2][r],acc[3][r]));
      m = fmaxf(m, __shfl_xor(m,1));
      m = fmaxf(m, __shfl_xor(m,2));
      m = fmaxf(m, __shfl_xor(m,4));
      m = fmaxf(m, __shfl_xor(m,8));
      float m_new = fmaxf(m_run[r], m);
      float alpha = __expf(m_run[r]-m_new);
      m_run[r] = m_new;
      float s = 0.f;
      #pragma unroll
      for(int t=0;t<4;t++){
        float p = __expf(acc[t][r]-m_new);
        acc[t][r] = p;
        s += p;
      }
      s += __shfl_xor(s,1);
      s += __shfl_xor(s,2);
      s += __shfl_xor(s,4);
      s += __shfl_xor(s,8);
      l_run[r] = l_run[r]*alpha + s;
      Oa0[r] *= alpha;
      Oa1[r] *= alpha;
      int q = lg*4 + r;
      #pragma unroll
      for(int t=0;t<4;t++)
        Pw[q*72 + 16*t + l15] = (short)f2bf(acc[t][r]);
    }

    #pragma unroll
    for(int chunk=0;chunk<2;chunk++){
      bf16x8 pf  = *(const bf16x8*)&Pw[l15*72 + chunk*32 + lg*8];
      bf16x8 vf0 = *(const bf16x8*)&Vs[(     l15)*72 + chunk*32 + lg*8];
      bf16x8 vf1 = *(const bf16x8*)&Vs[(16 + l15)*72 + chunk*32 + lg*8];
      Oa0 = __builtin_amdgcn_mfma_f32_16x16x32_bf16(pf, vf0, Oa0, 0,0,0);
      Oa1 = __builtin_amdgcn_mfma_f32_16x16x32_bf16(pf, vf1, Oa1, 0,0,0);
    }
  }

  #pragma unroll
  for(int r=0;r<4;r++){
    float inv = 1.0f/l_run[r];
    size_t row = q0 + w*16 + lg*4 + r;
    O[row*DD + h*HD_ +      l15] = f2bf(Oa0[r]*inv);
    O[row*DD + h*HD_ + 16 + l15] = f2bf(Oa1[r]*inv);
  }
}

// ---------------- gated fusion ----------------
__global__ __launch_bounds__(256) void gate_kernel(const float* __restrict__ hl,
    const float* __restrict__ hgl, const float* __restrict__ gw,
    const float* __restrict__ gb, float* __restrict__ h){
  __shared__ float sbuf[4];
  int n = blockIdx.x, d = threadIdx.x;
  float a = hl[(size_t)n*DD+d], b2 = hgl[(size_t)n*DD+d];
  float p = a*gw[d] + b2*gw[DD+d];
  float s = block_sum256(p, sbuf);
  float gg = 1.0f/(1.0f+__expf(-(s+gb[0])));
  h[(size_t)n*DD+d] = gg*a + (1.0f-gg)*b2;
}

// ---------------- column mean ----------------
__global__ __launch_bounds__(256) void mean_kernel(const float* __restrict__ o,
    float* __restrict__ mean){
  int d = threadIdx.x;
  int r0 = blockIdx.x*256;
  float acc = 0.f;
  for(int r=r0;r<r0+256;++r) acc += o[(size_t)r*DD+d];
  atomicAdd(&mean[d], acc*(1.0f/NN));
}

template<int EPI,int OUT>
static inline void mgemm(const unsigned short* A, const unsigned short* BT,
    const float* bias, const float* res, void* C, int M, int K, int N, hipStream_t s){
  hipLaunchKernelGGL((mgemm_kernel<EPI,OUT>), dim3(N/64, M/64), dim3(256), 0, s,
                     A, BT, bias, res, C, M, K, N);
}

extern "C" void kernel_launch(void* const* d_in, const int* in_sizes, int n_in,
                              void* d_out, int out_size, void* d_ws, size_t ws_size,
                              hipStream_t stream){
  const float* x         = (const float*)d_in[0];
  const int*   ei        = (const int*)  d_in[1];
  const float* edge_attr = (const float*)d_in[2];
  const float* attn_bias = (const float*)d_in[3];
  const float* in_w=(const float*)d_in[4];  const float* in_b=(const float*)d_in[5];
  const float* ew_w=(const float*)d_in[6];  const float* ew_b=(const float*)d_in[7];
  const float* lw =(const float*)d_in[8];   const float* lb =(const float*)d_in[9];
  const float* lng=(const float*)d_in[10];  const float* lnb=(const float*)d_in[11];
  const float* qw =(const float*)d_in[12];  const float* qb =(const float*)d_in[13];
  const float* kw =(const float*)d_in[14];  const float* kb =(const float*)d_in[15];
  const float* vw =(const float*)d_in[16];  const float* vb =(const float*)d_in[17];
  const float* ow =(const float*)d_in[18];  const float* ob =(const float*)d_in[19];
  const float* f1w=(const float*)d_in[20];  const float* f1b=(const float*)d_in[21];
  const float* f2w=(const float*)d_in[22];  const float* f2b=(const float*)d_in[23];
  const float* n1g=(const float*)d_in[24];  const float* n1b=(const float*)d_in[25];
  const float* n2g=(const float*)d_in[26];  const float* n2b=(const float*)d_in[27];
  const float* gw =(const float*)d_in[28];  const float* gb =(const float*)d_in[29];
  const float* fng=(const float*)d_in[30];  const float* fnb=(const float*)d_in[31];
  float* out = (float*)d_out;

  // ---- workspace layout ----
  char* Wp = (char*)d_ws;
  auto alloc = [&](size_t bytes){ char* p = Wp; Wp += (bytes + 255) & ~(size_t)255; return p; };
  const size_t ND = (size_t)NN*DD;
  unsigned short* Bt    = (unsigned short*)alloc((size_t)HH*NN*NN*2);   // 64 MiB
  unsigned short* qkv16 = (unsigned short*)alloc(3*ND*2);               // Qb|Kb|Vt
  unsigned short* Obf   = (unsigned short*)alloc(ND*2);
  unsigned short* xbf   = (unsigned short*)alloc((size_t)NN*DIN_*2);
  unsigned short* aggbf = (unsigned short*)alloc(ND*2);
  unsigned short* hnbf  = (unsigned short*)alloc(ND*2);
  unsigned short* ffbbf = (unsigned short*)alloc((size_t)NN*FF_*2);
  // bf16 transposed weights
  unsigned short* inT   = (unsigned short*)alloc((size_t)DD*DIN_*2);
  unsigned short* lwT   = (unsigned short*)alloc((size_t)LL*DD*DD*2);
  unsigned short* qkvT  = (unsigned short*)alloc((size_t)LL*3*DD*DD*2);
  unsigned short* owT   = (unsigned short*)alloc((size_t)LL*DD*DD*2);
  unsigned short* f1T   = (unsigned short*)alloc((size_t)LL*DD*FF_*2);
  unsigned short* f2T   = (unsigned short*)alloc((size_t)LL*FF_*DD*2);
  float* qkvb  = (float*)alloc((size_t)LL*768*4);
  // f32 activations
  float* h     = (float*)alloc(ND*4);
  float* bufB  = (float*)alloc(ND*4);
  float* hloc  = (float*)alloc(ND*4);
  float* hg    = (float*)alloc(ND*4);
  float* hgl   = (float*)alloc(ND*4);
  float* edge_w= (float*)alloc(EE*4);
  float* csr_c = (float*)alloc(EE*4);
  float* dinv  = (float*)alloc(NN*4);
  int* counts  = (int*)alloc(NN*4);
  int* cursor  = (int*)alloc(NN*4);
  int* row_ptr = (int*)alloc((NN+1)*4);
  int* csr_src = (int*)alloc(EE*4);

  // ---- preprocessing (identical every call) ----
  hipMemsetAsync(counts, 0, NN*sizeof(int), stream);
  hipMemsetAsync(cursor, 0, NN*sizeof(int), stream);
  hipLaunchKernelGGL(count_kernel, dim3(EE/256),dim3(256),0,stream, ei, counts);
  hipLaunchKernelGGL(scan_kernel,  dim3(1),dim3(1024),0,stream, counts, row_ptr, dinv);
  hipLaunchKernelGGL(edgew_kernel, dim3(EE/4),dim3(256),0,stream, edge_attr, ew_w, ew_b, edge_w);
  hipLaunchKernelGGL(bucket_kernel,dim3(EE/256),dim3(256),0,stream, ei, edge_w, dinv, row_ptr, cursor, csr_src, csr_c);
  hipLaunchKernelGGL(bias_prep_kernel, dim3(NN*NN/256),dim3(256),0,stream, attn_bias, Bt);

  // weight transposes (f32 [K][N] -> bf16 [N][K])
  hipLaunchKernelGGL(wtrans_kernel, dim3(DIN_/32, DD/32, 1),  dim3(256),0,stream, in_w, inT,  DIN_, DD, 0, 0, 0);
  hipLaunchKernelGGL(wtrans_kernel, dim3(DD/32, DD/32, LL),   dim3(256),0,stream, lw,   lwT,  DD, DD, (size_t)DD*DD, (size_t)DD*DD, 0);
  hipLaunchKernelGGL(wtrans_kernel, dim3(DD/32, DD/32, LL),   dim3(256),0,stream, qw,   qkvT, DD, DD, (size_t)DD*DD, (size_t)3*DD*DD, 0);
  hipLaunchKernelGGL(wtrans_kernel, dim3(DD/32, DD/32, LL),   dim3(256),0,stream, kw,   qkvT, DD, DD, (size_t)DD*DD, (size_t)3*DD*DD, 256);
  hipLaunchKernelGGL(wtrans_kernel, dim3(DD/32, DD/32, LL),   dim3(256),0,stream, vw,   qkvT, DD, DD, (size_t)DD*DD, (size_t)3*DD*DD, 512);
  hipLaunchKernelGGL(wtrans_kernel, dim3(DD/32, DD/32, LL),   dim3(256),0,stream, ow,   owT,  DD, DD, (size_t)DD*DD, (size_t)DD*DD, 0);
  hipLaunchKernelGGL(wtrans_kernel, dim3(DD/32, FF_/32, LL),  dim3(256),0,stream, f1w,  f1T,  DD, FF_, (size_t)DD*FF_, (size_t)DD*FF_, 0);
  hipLaunchKernelGGL(wtrans_kernel, dim3(FF_/32, DD/32, LL),  dim3(256),0,stream, f2w,  f2T,  FF_, DD, (size_t)FF_*DD, (size_t)FF_*DD, 0);
  hipLaunchKernelGGL(qkvb_kernel,  dim3(LL*768/256),dim3(256),0,stream, qb, kb, vb, qkvb);
  hipLaunchKernelGGL(cast_bf_kernel, dim3(NN*DIN_/256),dim3(256),0,stream, x, xbf, NN*DIN_);

  // h = x @ in_w + in_b   (f32 out)
  mgemm<0,0>(xbf, inT, in_b, nullptr, h, NN, DIN_, DD, stream);

  for(int i=0;i<LL;i++){
    const unsigned short* lwTi  = lwT  + (size_t)i*DD*DD;
    const unsigned short* qkvTi = qkvT + (size_t)i*3*DD*DD;
    const unsigned short* owTi  = owT  + (size_t)i*DD*DD;
    const unsigned short* f1Ti  = f1T  + (size_t)i*DD*FF_;
    const unsigned short* f2Ti  = f2T  + (size_t)i*FF_*DD;

    // local GCN branch
    hipLaunchKernelGGL(agg_kernel, dim3(NN),dim3(256),0,stream, h, row_ptr, csr_src, csr_c, dinv, aggbf);
    mgemm<1,0>(aggbf, lwTi, lb+i*DD, nullptr, bufB, NN, DD, DD, stream);
    hipLaunchKernelGGL((ln_kernel<0>), dim3(NN),dim3(256),0,stream, bufB, lng+i*DD, lnb+i*DD, hloc);

    // global attention branch
    hipLaunchKernelGGL((ln_kernel<1>), dim3(NN),dim3(256),0,stream, h, n1g+i*DD, n1b+i*DD, hnbf);
    mgemm<0,2>(hnbf, qkvTi, qkvb+(size_t)i*768, nullptr, qkv16, NN, DD, 768, stream);
    hipLaunchKernelGGL(attn_mfma_kernel, dim3(NN/TQA, HH),dim3(256),0,stream,
                       qkv16, qkv16+ND, qkv16+2*ND, Bt, Obf);
    mgemm<2,0>(Obf, owTi, ob+i*DD, h, hg, NN, DD, DD, stream);

    hipLaunchKernelGGL((ln_kernel<1>), dim3(NN),dim3(256),0,stream, hg, n2g+i*DD, n2b+i*DD, hnbf);
    mgemm<1,1>(hnbf, f1Ti, f1b+i*FF_, nullptr, ffbbf, NN, DD, FF_, stream);
    mgemm<2,0>(ffbbf, f2Ti, f2b+i*DD, hg, hgl, NN, FF_, DD, stream);

    // gated fusion -> h
    hipLaunchKernelGGL(gate_kernel, dim3(NN),dim3(256),0,stream, hloc, hgl, gw+(size_t)i*2*DD, gb+i, h);
  }

  // final LN -> out[0:NN*DD], then column mean -> out[NN*DD : +DD]
  hipLaunchKernelGGL((ln_kernel<0>), dim3(NN),dim3(256),0,stream, h, fng, fnb, out);
  hipMemsetAsync(out + ND, 0, DD*sizeof(float), stream);
  hipLaunchKernelGGL(mean_kernel, dim3(NN/256),dim3(256),0,stream, out, out + ND);
}